// Round 5
// baseline (892.234 us; speedup 1.0000x reference)
//
#include <hip/hip_runtime.h>

#define N_NODES   100000
#define N_EDGES   3200000
#define NUM_GRAPHS 1024
#define F_IN      128
#define EMB       32

#define NRANGE    4
#define RANGE_SZ  25000                    // src ranges for phased gather
#define NKEY      (N_NODES * NRANGE)       // 400000 CSR buckets (dst*4 + srcRange)

#define NGROUP    32                       // dst buckets (bucket%8 = XCD under round-robin)
#define GROUP_SZ  3125                     // N_NODES / NGROUP
#define BCAP      104000                   // mean 100000 + ~13 sigma
#define PART_TILE 2048
#define PART_NB   ((N_EDGES + PART_TILE - 1) / PART_TILE)   // 1563
#define FILL_CPB  40                       // chunks per bucket -> 1280 blocks

#define SCAN_TILE 1024
#define SCAN_NB   ((NKEY + SCAN_TILE - 1) / SCAN_TILE)      // 391

// ---- init: zero deg2 + bucket counters; rp2 sentinel ----
__global__ void init_k(int* __restrict__ deg2, int* __restrict__ rp2,
                       int* __restrict__ bucketCnt) {
    int i = blockIdx.x * blockDim.x + threadIdx.x;
    if (i < NKEY) deg2[i] = 0;
    if (i < NGROUP) bucketCnt[i] = 0;
    if (i == 0) rp2[NKEY] = N_EDGES;
}

// ---- partition edges into 32 dst-buckets (packed 4B) + fold in deg2 histogram ----
__global__ __launch_bounds__(256) void partition_k(const int* __restrict__ src,
                                                   const int* __restrict__ dst,
                                                   int* __restrict__ deg2,
                                                   int* __restrict__ bucketCnt,
                                                   unsigned* __restrict__ bEdges) {
    __shared__ int hist[NGROUP];
    __shared__ int lbase[NGROUP + 1];
    __shared__ int gbase[NGROUP];
    __shared__ unsigned stage[PART_TILE];
    int t = threadIdx.x;
    int base = blockIdx.x * PART_TILE;
    if (t < NGROUP) hist[t] = 0;
    __syncthreads();
    unsigned val[8]; int bk[8], rk[8];
#pragma unroll
    for (int i = 0; i < 8; ++i) {
        int e = base + i * 256 + t;
        bk[i] = -1;
        if (e < N_EDGES) {
            int s = __builtin_nontemporal_load(src + e);
            int d = __builtin_nontemporal_load(dst + e);
            int b = (int)((unsigned)d / GROUP_SZ);
            val[i] = ((unsigned)(d - b * GROUP_SZ) << 17) | (unsigned)s;
            atomicAdd(&deg2[d * NRANGE + (int)((unsigned)s / RANGE_SZ)], 1);
            bk[i] = b;
            rk[i] = atomicAdd(&hist[b], 1);          // LDS atomic
        }
    }
    __syncthreads();
    if (t == 0) {
        int run = 0;
        for (int b = 0; b < NGROUP; ++b) { lbase[b] = run; run += hist[b]; }
        lbase[NGROUP] = run;
    }
    if (t < NGROUP && hist[t] > 0) gbase[t] = atomicAdd(&bucketCnt[t], hist[t]);
    __syncthreads();
#pragma unroll
    for (int i = 0; i < 8; ++i)
        if (bk[i] >= 0) stage[lbase[bk[i]] + rk[i]] = val[i];
    __syncthreads();
    int total = lbase[NGROUP];
    for (int j = t; j < total; j += 256) {
        int lo = 0, hi = NGROUP;                     // lbase[lo] <= j < lbase[hi]
        while (hi - lo > 1) { int mid = (lo + hi) >> 1; if (lbase[mid] <= j) lo = mid; else hi = mid; }
        int off = gbase[lo] + (j - lbase[lo]);
        if (off < BCAP) __builtin_nontemporal_store(stage[j], &bEdges[lo * BCAP + off]);
    }
}

// ---- scan phase 1: per-tile sums ----
__global__ __launch_bounds__(256) void scan_reduce_k(const int* __restrict__ deg2,
                                                     int* __restrict__ partial) {
    __shared__ int l[256];
    int b = blockIdx.x, t = threadIdx.x;
    int base = b * SCAN_TILE + t * 4;
    int s = 0;
    if (base < NKEY) {
        int4 v = *(const int4*)(deg2 + base);
        s = v.x + v.y + v.z + v.w;
    }
    l[t] = s; __syncthreads();
    for (int off = 128; off > 0; off >>= 1) {
        if (t < off) l[t] += l[t + off];
        __syncthreads();
    }
    if (t == 0) partial[b] = l[0];
}

// ---- scan phase 2: exclusive scan of 391 partials ----
__global__ __launch_bounds__(512) void scan_partials_k(const int* __restrict__ partial,
                                                       int* __restrict__ blockoff) {
    __shared__ int l[512];
    int t = threadIdx.x;
    l[t] = (t < SCAN_NB) ? partial[t] : 0;
    __syncthreads();
    for (int off = 1; off < 512; off <<= 1) {
        int v = l[t];
        int a = (t >= off) ? l[t - off] : 0;
        __syncthreads();
        l[t] = v + a;
        __syncthreads();
    }
    if (t < SCAN_NB) blockoff[t] = (t > 0) ? l[t - 1] : 0;
}

// ---- scan phase 3: apply -> rp2 / pos2 / dinv ----
__global__ __launch_bounds__(256) void scan_apply_k(const int* __restrict__ deg2,
                                                    const int* __restrict__ blockoff,
                                                    int* __restrict__ rp2,
                                                    int* __restrict__ pos2,
                                                    float* __restrict__ dinv) {
    __shared__ int l[256];
    int b = blockIdx.x, t = threadIdx.x;
    int base = b * SCAN_TILE + t * 4;
    int d0 = 0, d1 = 0, d2 = 0, d3 = 0;
    if (base < NKEY) {
        int4 v = *(const int4*)(deg2 + base);
        d0 = v.x; d1 = v.y; d2 = v.z; d3 = v.w;
    }
    l[t] = d0 + d1 + d2 + d3;
    __syncthreads();
    for (int off = 1; off < 256; off <<= 1) {
        int v = l[t];
        int a = (t >= off) ? l[t - off] : 0;
        __syncthreads();
        l[t] = v + a;
        __syncthreads();
    }
    if (base < NKEY) {
        int run = blockoff[b] + ((t > 0) ? l[t - 1] : 0);
        int node = base >> 2;
        dinv[node] = rsqrtf((float)(d0 + d1 + d2 + d3 + 1));
        rp2[base + 0] = run; pos2[base + 0] = run; run += d0;
        rp2[base + 1] = run; pos2[base + 1] = run; run += d1;
        rp2[base + 2] = run; pos2[base + 2] = run; run += d2;
        rp2[base + 3] = run; pos2[base + 3] = run; run += d3;
    }
}

// ---- CSR fill from bucketed edges: bucket = blockIdx%32 (XCD-affine) ----
__global__ __launch_bounds__(256) void fill_k(const unsigned* __restrict__ bEdges,
                                              const int* __restrict__ bucketCnt,
                                              int* __restrict__ pos2,
                                              int* __restrict__ col) {
    int b = blockIdx.x & (NGROUP - 1);
    int chunk = blockIdx.x >> 5;
    int cnt = bucketCnt[b];
    if (cnt > BCAP) cnt = BCAP;
    const unsigned* be = bEdges + b * BCAP;
    for (int i = chunk * 256 + threadIdx.x; i < cnt; i += FILL_CPB * 256) {
        unsigned v = __builtin_nontemporal_load(be + i);
        unsigned s = v & 0x1FFFFu;
        unsigned d = (unsigned)b * GROUP_SZ + (v >> 17);
        int slot = atomicAdd(&pos2[d * NRANGE + s / RANGE_SZ], 1);
        col[slot] = (int)s;
    }
}

// ---- layer 0 transform: tmp[n][j] = (x[n,:] @ W0[:,j]) * dinv[n] ----
__global__ void transform0_k(const float* __restrict__ x, const float* __restrict__ W0,
                             const float* __restrict__ dinv, float* __restrict__ tmp) {
    int i = blockIdx.x * blockDim.x + threadIdx.x;
    if (i >= N_NODES * EMB) return;
    int n = i >> 5, j = i & 31;
    const float* xr = x + (long long)n * F_IN;
    float acc = 0.f;
#pragma unroll 8
    for (int k = 0; k < F_IN; ++k) acc += xr[k] * W0[k * EMB + j];
    tmp[i] = acc * dinv[n];
}

// ---- hidden transform ----
__global__ void transform_k(const float* __restrict__ h, const float* __restrict__ W,
                            const float* __restrict__ dinv, float* __restrict__ tmp) {
    int i = blockIdx.x * blockDim.x + threadIdx.x;
    if (i >= N_NODES * EMB) return;
    int n = i >> 5, j = i & 31;
    const float* hr = h + n * EMB;
    float acc = 0.f;
#pragma unroll
    for (int k = 0; k < EMB; ++k) acc += hr[k] * W[k * EMB + j];
    tmp[i] = acc * dinv[n];
}

// ---- phased gather: phase r touches only tmp slice [r*25000,(r+1)*25000) ----
template <int MODE>   // 0: acc=tmp(self)  1: acc=h  2: acc=h then finalize
__global__ void gatherp_k(const int* __restrict__ rp2, const int* __restrict__ col,
                          const float4* __restrict__ tmp4, const float* __restrict__ dinv,
                          const float* __restrict__ bias, float4* __restrict__ h4, int r) {
    int i = blockIdx.x * blockDim.x + threadIdx.x;
    if (i >= N_NODES * 8) return;
    int n = i >> 3, q = i & 7;
    int beg = rp2[n * 4 + r], end = rp2[n * 4 + r + 1];
    float4 acc = (MODE == 0) ? tmp4[i] : h4[i];
    int k = beg;
    for (; k + 4 <= end; k += 4) {
        int s0 = col[k], s1 = col[k + 1], s2 = col[k + 2], s3 = col[k + 3];
        float4 v0 = tmp4[s0 * 8 + q];
        float4 v1 = tmp4[s1 * 8 + q];
        float4 v2 = tmp4[s2 * 8 + q];
        float4 v3 = tmp4[s3 * 8 + q];
        acc.x += (v0.x + v1.x) + (v2.x + v3.x);
        acc.y += (v0.y + v1.y) + (v2.y + v3.y);
        acc.z += (v0.z + v1.z) + (v2.z + v3.z);
        acc.w += (v0.w + v1.w) + (v2.w + v3.w);
    }
    for (; k < end; ++k) {
        int s = col[k];
        float4 v = tmp4[s * 8 + q];
        acc.x += v.x; acc.y += v.y; acc.z += v.z; acc.w += v.w;
    }
    if (MODE == 2) {
        float dn = dinv[n];
        float4 bb = ((const float4*)bias)[q];
        float4 rr;
        rr.x = acc.x * dn + bb.x;
        rr.y = acc.y * dn + bb.y;
        rr.z = acc.z * dn + bb.z;
        rr.w = acc.w * dn + bb.w;
        rr.x = rr.x > 0.f ? rr.x : 0.01f * rr.x;
        rr.y = rr.y > 0.f ? rr.y : 0.01f * rr.y;
        rr.z = rr.z > 0.f ? rr.z : 0.01f * rr.z;
        rr.w = rr.w > 0.f ? rr.w : 0.01f * rr.w;
        h4[i] = rr;
    } else {
        h4[i] = acc;
    }
}

// ---- fused pool + head (batch_index sorted) ----
__global__ __launch_bounds__(256) void pool_head_k(const float* __restrict__ h,
                                                   const int* __restrict__ batch,
                                                   const float* __restrict__ Wout,
                                                   const float* __restrict__ bout,
                                                   float* __restrict__ out) {
    int g = blockIdx.x;
    __shared__ int sbeg, send;
    if (threadIdx.x == 0) {
        int lo = 0, hi = N_NODES;
        while (lo < hi) { int mid = (lo + hi) >> 1; if (batch[mid] < g) lo = mid + 1; else hi = mid; }
        sbeg = lo;
        hi = N_NODES;
        while (lo < hi) { int mid = (lo + hi) >> 1; if (batch[mid] < g + 1) lo = mid + 1; else hi = mid; }
        send = lo;
    }
    __syncthreads();
    int beg = sbeg, end = send;
    int t = threadIdx.x, c = t & 31, r = t >> 5;
    float m = -INFINITY;
    for (int n = beg + r; n < end; n += 8) m = fmaxf(m, h[n * EMB + c]);
    __shared__ float red[256];
    red[t] = m;
    __syncthreads();
    if (t < 128) red[t] = fmaxf(red[t], red[t + 128]);
    __syncthreads();
    if (t < 64) red[t] = fmaxf(red[t], red[t + 64]);
    __syncthreads();
    if (t < 32) {
        m = fmaxf(red[t], red[t + 32]);
        out[NUM_GRAPHS + g * EMB + c] = m;
        float p = m * Wout[c];
#pragma unroll
        for (int o = 16; o > 0; o >>= 1) p += __shfl_xor(p, o, 32);
        if (c == 0) out[g] = p + bout[0];
    }
}

extern "C" void kernel_launch(void* const* d_in, const int* in_sizes, int n_in,
                              void* d_out, int out_size, void* d_ws, size_t ws_size,
                              hipStream_t stream) {
    const float* x     = (const float*)d_in[0];
    const int*   ei    = (const int*)d_in[1];
    const int*   src   = ei;
    const int*   dst   = ei + N_EDGES;
    const int*   batch = (const int*)d_in[2];
    const float* W0    = (const float*)d_in[3];
    const float* b0    = (const float*)d_in[4];
    const float* Ws    = (const float*)d_in[5];
    const float* bs    = (const float*)d_in[6];
    const float* Wout  = (const float*)d_in[7];
    const float* bout  = (const float*)d_in[8];
    float* out = (float*)d_out;

    char* ws = (char*)d_ws;
    int*   rp2      = (int*)ws;   ws += (size_t)(NKEY + 4) * 4;        // 1.6 MB (16B-mult)
    int*   col      = (int*)ws;   ws += (size_t)N_EDGES * 4;           // 12.8 MB
    float* dinv     = (float*)ws; ws += (size_t)N_NODES * 4;           // 400 KB
    float* tmp      = (float*)ws; ws += (size_t)N_NODES * EMB * 4;     // 12.8 MB
    float* h        = (float*)ws; ws += (size_t)N_NODES * EMB * 4;     // 12.8 MB
    int*   partial  = (int*)ws;   ws += 2048;
    int*   blockoff = (int*)ws;   ws += 2048;
    int*   bucketCnt= (int*)ws;   ws += 256;
    // scratch aliases over tmp+h (all dead before transform0/gather phase 0):
    char* scratch = (char*)tmp;
    int*      deg2   = (int*)scratch;                        // 1.6 MB
    int*      pos2   = (int*)(scratch + 1600000);            // 1.6 MB
    unsigned* bEdges = (unsigned*)(scratch + 3200000);       // 13.3 MB (spills into h; dead)

    const int B = 256;
    const int NC_g = (N_NODES * EMB + B - 1) / B;
    const int G8_g = (N_NODES * 8 + B - 1) / B;
    const int NK_g = (NKEY + B - 1) / B;

    init_k<<<NK_g, B, 0, stream>>>(deg2, rp2, bucketCnt);
    partition_k<<<PART_NB, B, 0, stream>>>(src, dst, deg2, bucketCnt, bEdges);
    scan_reduce_k<<<SCAN_NB, B, 0, stream>>>(deg2, partial);
    scan_partials_k<<<1, 512, 0, stream>>>(partial, blockoff);
    scan_apply_k<<<SCAN_NB, B, 0, stream>>>(deg2, blockoff, rp2, pos2, dinv);
    fill_k<<<NGROUP * FILL_CPB, B, 0, stream>>>(bEdges, bucketCnt, pos2, col);

    // layer 0: 128 -> 32
    transform0_k<<<NC_g, B, 0, stream>>>(x, W0, dinv, tmp);
    gatherp_k<0><<<G8_g, B, 0, stream>>>(rp2, col, (const float4*)tmp, dinv, b0, (float4*)h, 0);
    gatherp_k<1><<<G8_g, B, 0, stream>>>(rp2, col, (const float4*)tmp, dinv, b0, (float4*)h, 1);
    gatherp_k<1><<<G8_g, B, 0, stream>>>(rp2, col, (const float4*)tmp, dinv, b0, (float4*)h, 2);
    gatherp_k<2><<<G8_g, B, 0, stream>>>(rp2, col, (const float4*)tmp, dinv, b0, (float4*)h, 3);

    // hidden layers: 32 -> 32
    for (int l = 0; l < 3; ++l) {
        const float* bl = bs + l * EMB;
        transform_k<<<NC_g, B, 0, stream>>>(h, Ws + l * EMB * EMB, dinv, tmp);
        gatherp_k<0><<<G8_g, B, 0, stream>>>(rp2, col, (const float4*)tmp, dinv, bl, (float4*)h, 0);
        gatherp_k<1><<<G8_g, B, 0, stream>>>(rp2, col, (const float4*)tmp, dinv, bl, (float4*)h, 1);
        gatherp_k<1><<<G8_g, B, 0, stream>>>(rp2, col, (const float4*)tmp, dinv, bl, (float4*)h, 2);
        gatherp_k<2><<<G8_g, B, 0, stream>>>(rp2, col, (const float4*)tmp, dinv, bl, (float4*)h, 3);
    }

    pool_head_k<<<NUM_GRAPHS, B, 0, stream>>>(h, batch, Wout, bout, out);
}

// Round 6
// 663.048 us; speedup vs baseline: 1.3457x; 1.3457x over previous
//
#include <hip/hip_runtime.h>

#define N_NODES   100000
#define N_EDGES   3200000
#define NUM_GRAPHS 1024
#define F_IN      128
#define EMB       32

#define NRANGE    4
#define RANGE_SZ  25000                    // src ranges for phased gather
#define NKEY      (N_NODES * NRANGE)       // 400000 CSR keys (dst*4 + srcRange)

#define NGROUP    256                      // dst buckets
#define GROUP_SZ  391                      // ceil-ish: 256*391 = 100096 >= N
#define BCAP      13824                    // mean 12512 + ~11.7 sigma
#define FB        1024                     // fill block threads
#define FILL_ITER 14                       // ceil(BCAP/FB)

#define PART_TILE 8192
#define PART_THREADS 512
#define PART_NB   ((N_EDGES + PART_TILE - 1) / PART_TILE)   // 391

// ---- tiny init: zero bucket counters; rp2 sentinel ----
__global__ void init_k(int* __restrict__ bucketCnt, int* __restrict__ rp2) {
    int i = threadIdx.x;
    if (i < NGROUP) bucketCnt[i] = 0;
    if (i == 0) rp2[NKEY] = N_EDGES;
}

// ---- partition edges into 256 dst-buckets, packed 4B, coalesced nt writes ----
__global__ __launch_bounds__(PART_THREADS) void partition_k(const int* __restrict__ src,
                                                            const int* __restrict__ dst,
                                                            int* __restrict__ bucketCnt,
                                                            unsigned* __restrict__ bEdges) {
    __shared__ unsigned stage[PART_TILE];
    __shared__ int hist[NGROUP];
    __shared__ int sc[NGROUP];
    __shared__ int lbase[NGROUP + 1];
    __shared__ int gbase[NGROUP];
    int t = threadIdx.x;
    int base = blockIdx.x * PART_TILE;
    for (int k = t; k < NGROUP; k += PART_THREADS) hist[k] = 0;
    __syncthreads();
    unsigned val[16]; int bk[16], rk[16];
#pragma unroll
    for (int i = 0; i < 16; ++i) {
        int e = base + i * PART_THREADS + t;
        bk[i] = -1;
        if (e < N_EDGES) {
            unsigned s = (unsigned)__builtin_nontemporal_load(src + e);
            unsigned d = (unsigned)__builtin_nontemporal_load(dst + e);
            int b = (int)(d / GROUP_SZ);
            val[i] = ((d - (unsigned)b * GROUP_SZ) << 17) | s;
            bk[i] = b;
            rk[i] = atomicAdd(&hist[b], 1);            // LDS atomic
        }
    }
    __syncthreads();
    if (t < NGROUP) sc[t] = hist[t];
    __syncthreads();
    for (int off = 1; off < NGROUP; off <<= 1) {       // Hillis inclusive scan
        int v = 0;
        if (t < NGROUP) v = sc[t] + ((t >= off) ? sc[t - off] : 0);
        __syncthreads();
        if (t < NGROUP) sc[t] = v;
        __syncthreads();
    }
    if (t < NGROUP) {
        lbase[t] = sc[t] - hist[t];
        if (hist[t] > 0) gbase[t] = atomicAdd(&bucketCnt[t], hist[t]);
        if (t == NGROUP - 1) lbase[NGROUP] = sc[t];
    }
    __syncthreads();
#pragma unroll
    for (int i = 0; i < 16; ++i)
        if (bk[i] >= 0) stage[lbase[bk[i]] + rk[i]] = val[i];
    __syncthreads();
    int total = lbase[NGROUP];
    for (int j = t; j < total; j += PART_THREADS) {
        int lo = 0, hi = NGROUP;                       // lbase[lo] <= j < lbase[lo+1]
        while (hi - lo > 1) { int mid = (lo + hi) >> 1; if (lbase[mid] <= j) lo = mid; else hi = mid; }
        int off = gbase[lo] + (j - lbase[lo]);
        if (off < BCAP) __builtin_nontemporal_store(stage[j], &bEdges[(size_t)lo * BCAP + off]);
    }
}

// ---- per-bucket LDS counting sort: writes rp2 slice, dinv, col (all coalesced) ----
__global__ __launch_bounds__(FB) void fill_k(const unsigned* __restrict__ bEdges,
                                             const int* __restrict__ bucketCnt,
                                             int* __restrict__ rp2,
                                             float* __restrict__ dinv,
                                             int* __restrict__ col) {
    __shared__ int cur[GROUP_SZ * 4];      // 1564 key cursors
    __shared__ int nodesum[512];           // scan scratch (buckets, then node sums)
    __shared__ unsigned lout[BCAP];        // 55.3 KB staging for sorted edges
    __shared__ int sColBase;
    int b = blockIdx.x, t = threadIdx.x;

    // bucket col base = prefix of bucketCnt (redundant per-block 256-scan)
    if (t < NGROUP) { int c = bucketCnt[t]; nodesum[t] = c > BCAP ? BCAP : c; }
    else if (t < 512) nodesum[t] = 0;
    __syncthreads();
    for (int off = 1; off < NGROUP; off <<= 1) {
        int v = 0;
        if (t < NGROUP) v = nodesum[t] + ((t >= off) ? nodesum[t - off] : 0);
        __syncthreads();
        if (t < NGROUP) nodesum[t] = v;
        __syncthreads();
    }
    if (t == 0) sColBase = (b > 0) ? nodesum[b - 1] : 0;
    __syncthreads();
    int colBase = sColBase;

    int nb = N_NODES - b * GROUP_SZ; if (nb > GROUP_SZ) nb = GROUP_SZ;
    int nk = nb * 4;
    for (int k = t; k < nk; k += FB) cur[k] = 0;
    __syncthreads();

    int cnt = bucketCnt[b]; if (cnt > BCAP) cnt = BCAP;
    const unsigned* be = bEdges + (size_t)b * BCAP;
    unsigned val[FILL_ITER];
#pragma unroll
    for (int i = 0; i < FILL_ITER; ++i) {
        int idx = i * FB + t;
        val[i] = 0xFFFFFFFFu;                          // impossible packed value
        if (idx < cnt) {
            unsigned v = __builtin_nontemporal_load(be + idx);
            val[i] = v;
            unsigned key = (v >> 17) * NRANGE + (v & 0x1FFFFu) / RANGE_SZ;
            atomicAdd(&cur[key], 1);                   // LDS histogram
        }
    }
    __syncthreads();

    // node sums -> dinv; scan node sums -> key prefixes -> rp2 + cursors
    int h0 = 0, h1 = 0, h2 = 0, h3 = 0;
    if (t < nb) {
        h0 = cur[t * 4]; h1 = cur[t * 4 + 1]; h2 = cur[t * 4 + 2]; h3 = cur[t * 4 + 3];
        int dsum = h0 + h1 + h2 + h3;
        nodesum[t] = dsum;
        dinv[b * GROUP_SZ + t] = rsqrtf((float)(dsum + 1));
    } else if (t < 512) nodesum[t] = 0;
    __syncthreads();
    for (int off = 1; off < 512; off <<= 1) {
        int v = 0;
        if (t < 512) v = nodesum[t] + ((t >= off) ? nodesum[t - off] : 0);
        __syncthreads();
        if (t < 512) nodesum[t] = v;
        __syncthreads();
    }
    if (t < nb) {
        int p0 = (t > 0) ? nodesum[t - 1] : 0;
        int p1 = p0 + h0, p2 = p1 + h1, p3 = p2 + h2;
        int kb = (b * GROUP_SZ + t) * 4;
        int4 w; w.x = colBase + p0; w.y = colBase + p1; w.z = colBase + p2; w.w = colBase + p3;
        *(int4*)(rp2 + kb) = w;
        cur[t * 4] = p0; cur[t * 4 + 1] = p1; cur[t * 4 + 2] = p2; cur[t * 4 + 3] = p3;
    }
    __syncthreads();

    // scatter within LDS
#pragma unroll
    for (int i = 0; i < FILL_ITER; ++i) {
        unsigned v = val[i];
        if (v != 0xFFFFFFFFu) {
            unsigned key = (v >> 17) * NRANGE + (v & 0x1FFFFu) / RANGE_SZ;
            int slot = atomicAdd(&cur[key], 1);
            lout[slot] = v & 0x1FFFFu;
        }
    }
    __syncthreads();

    // stream sorted slice to col — fully coalesced
    for (int i = t; i < cnt; i += FB)
        __builtin_nontemporal_store((int)lout[i], col + colBase + i);
}

// ---- layer 0 transform: tmp[n][j] = (x[n,:] @ W0[:,j]) * dinv[n] ----
__global__ void transform0_k(const float* __restrict__ x, const float* __restrict__ W0,
                             const float* __restrict__ dinv, float* __restrict__ tmp) {
    int i = blockIdx.x * blockDim.x + threadIdx.x;
    if (i >= N_NODES * EMB) return;
    int n = i >> 5, j = i & 31;
    const float* xr = x + (long long)n * F_IN;
    float acc = 0.f;
#pragma unroll 8
    for (int k = 0; k < F_IN; ++k) acc += xr[k] * W0[k * EMB + j];
    tmp[i] = acc * dinv[n];
}

// ---- hidden transform ----
__global__ void transform_k(const float* __restrict__ h, const float* __restrict__ W,
                            const float* __restrict__ dinv, float* __restrict__ tmp) {
    int i = blockIdx.x * blockDim.x + threadIdx.x;
    if (i >= N_NODES * EMB) return;
    int n = i >> 5, j = i & 31;
    const float* hr = h + n * EMB;
    float acc = 0.f;
#pragma unroll
    for (int k = 0; k < EMB; ++k) acc += hr[k] * W[k * EMB + j];
    tmp[i] = acc * dinv[n];
}

// ---- phased gather: phase r touches only tmp slice [r*25000,(r+1)*25000) ----
template <int MODE>   // 0: acc=tmp(self)  1: acc=h  2: acc=h then finalize
__global__ void gatherp_k(const int* __restrict__ rp2, const int* __restrict__ col,
                          const float4* __restrict__ tmp4, const float* __restrict__ dinv,
                          const float* __restrict__ bias, float4* __restrict__ h4, int r) {
    int i = blockIdx.x * blockDim.x + threadIdx.x;
    if (i >= N_NODES * 8) return;
    int n = i >> 3, q = i & 7;
    int beg = rp2[n * 4 + r], end = rp2[n * 4 + r + 1];
    float4 acc = (MODE == 0) ? tmp4[i] : h4[i];
    int k = beg;
    for (; k + 4 <= end; k += 4) {
        int s0 = col[k], s1 = col[k + 1], s2 = col[k + 2], s3 = col[k + 3];
        float4 v0 = tmp4[s0 * 8 + q];
        float4 v1 = tmp4[s1 * 8 + q];
        float4 v2 = tmp4[s2 * 8 + q];
        float4 v3 = tmp4[s3 * 8 + q];
        acc.x += (v0.x + v1.x) + (v2.x + v3.x);
        acc.y += (v0.y + v1.y) + (v2.y + v3.y);
        acc.z += (v0.z + v1.z) + (v2.z + v3.z);
        acc.w += (v0.w + v1.w) + (v2.w + v3.w);
    }
    for (; k < end; ++k) {
        int s = col[k];
        float4 v = tmp4[s * 8 + q];
        acc.x += v.x; acc.y += v.y; acc.z += v.z; acc.w += v.w;
    }
    if (MODE == 2) {
        float dn = dinv[n];
        float4 bb = ((const float4*)bias)[q];
        float4 rr;
        rr.x = acc.x * dn + bb.x;
        rr.y = acc.y * dn + bb.y;
        rr.z = acc.z * dn + bb.z;
        rr.w = acc.w * dn + bb.w;
        rr.x = rr.x > 0.f ? rr.x : 0.01f * rr.x;
        rr.y = rr.y > 0.f ? rr.y : 0.01f * rr.y;
        rr.z = rr.z > 0.f ? rr.z : 0.01f * rr.z;
        rr.w = rr.w > 0.f ? rr.w : 0.01f * rr.w;
        h4[i] = rr;
    } else {
        h4[i] = acc;
    }
}

// ---- fused pool + head (batch_index sorted) ----
__global__ __launch_bounds__(256) void pool_head_k(const float* __restrict__ h,
                                                   const int* __restrict__ batch,
                                                   const float* __restrict__ Wout,
                                                   const float* __restrict__ bout,
                                                   float* __restrict__ out) {
    int g = blockIdx.x;
    __shared__ int sbeg, send;
    if (threadIdx.x == 0) {
        int lo = 0, hi = N_NODES;
        while (lo < hi) { int mid = (lo + hi) >> 1; if (batch[mid] < g) lo = mid + 1; else hi = mid; }
        sbeg = lo;
        hi = N_NODES;
        while (lo < hi) { int mid = (lo + hi) >> 1; if (batch[mid] < g + 1) lo = mid + 1; else hi = mid; }
        send = lo;
    }
    __syncthreads();
    int beg = sbeg, end = send;
    int t = threadIdx.x, c = t & 31, r = t >> 5;
    float m = -INFINITY;
    for (int n = beg + r; n < end; n += 8) m = fmaxf(m, h[n * EMB + c]);
    __shared__ float red[256];
    red[t] = m;
    __syncthreads();
    if (t < 128) red[t] = fmaxf(red[t], red[t + 128]);
    __syncthreads();
    if (t < 64) red[t] = fmaxf(red[t], red[t + 64]);
    __syncthreads();
    if (t < 32) {
        m = fmaxf(red[t], red[t + 32]);
        out[NUM_GRAPHS + g * EMB + c] = m;
        float p = m * Wout[c];
#pragma unroll
        for (int o = 16; o > 0; o >>= 1) p += __shfl_xor(p, o, 32);
        if (c == 0) out[g] = p + bout[0];
    }
}

extern "C" void kernel_launch(void* const* d_in, const int* in_sizes, int n_in,
                              void* d_out, int out_size, void* d_ws, size_t ws_size,
                              hipStream_t stream) {
    const float* x     = (const float*)d_in[0];
    const int*   ei    = (const int*)d_in[1];
    const int*   src   = ei;
    const int*   dst   = ei + N_EDGES;
    const int*   batch = (const int*)d_in[2];
    const float* W0    = (const float*)d_in[3];
    const float* b0    = (const float*)d_in[4];
    const float* Ws    = (const float*)d_in[5];
    const float* bs    = (const float*)d_in[6];
    const float* Wout  = (const float*)d_in[7];
    const float* bout  = (const float*)d_in[8];
    float* out = (float*)d_out;

    char* ws = (char*)d_ws;
    int*   rp2      = (int*)ws;   ws += (size_t)(NKEY + 4) * 4;        // 1.6 MB
    int*   col      = (int*)ws;   ws += (size_t)N_EDGES * 4;           // 12.8 MB
    float* dinv     = (float*)ws; ws += (size_t)N_NODES * 4;           // 400 KB
    float* tmp      = (float*)ws; ws += (size_t)N_NODES * EMB * 4;     // 12.8 MB
    float* h        = (float*)ws; ws += (size_t)N_NODES * EMB * 4;     // 12.8 MB
    int*   bucketCnt= (int*)ws;   ws += 1024;                          // 256 ints
    // bEdges (14.2 MB) aliases tmp+h — dead before transform0 / gather phase 0
    unsigned* bEdges = (unsigned*)tmp;

    const int B = 256;
    const int NC_g = (N_NODES * EMB + B - 1) / B;
    const int G8_g = (N_NODES * 8 + B - 1) / B;

    init_k<<<1, B, 0, stream>>>(bucketCnt, rp2);
    partition_k<<<PART_NB, PART_THREADS, 0, stream>>>(src, dst, bucketCnt, bEdges);
    fill_k<<<NGROUP, FB, 0, stream>>>(bEdges, bucketCnt, rp2, dinv, col);

    // layer 0: 128 -> 32
    transform0_k<<<NC_g, B, 0, stream>>>(x, W0, dinv, tmp);
    gatherp_k<0><<<G8_g, B, 0, stream>>>(rp2, col, (const float4*)tmp, dinv, b0, (float4*)h, 0);
    gatherp_k<1><<<G8_g, B, 0, stream>>>(rp2, col, (const float4*)tmp, dinv, b0, (float4*)h, 1);
    gatherp_k<1><<<G8_g, B, 0, stream>>>(rp2, col, (const float4*)tmp, dinv, b0, (float4*)h, 2);
    gatherp_k<2><<<G8_g, B, 0, stream>>>(rp2, col, (const float4*)tmp, dinv, b0, (float4*)h, 3);

    // hidden layers: 32 -> 32
    for (int l = 0; l < 3; ++l) {
        const float* bl = bs + l * EMB;
        transform_k<<<NC_g, B, 0, stream>>>(h, Ws + l * EMB * EMB, dinv, tmp);
        gatherp_k<0><<<G8_g, B, 0, stream>>>(rp2, col, (const float4*)tmp, dinv, bl, (float4*)h, 0);
        gatherp_k<1><<<G8_g, B, 0, stream>>>(rp2, col, (const float4*)tmp, dinv, bl, (float4*)h, 1);
        gatherp_k<1><<<G8_g, B, 0, stream>>>(rp2, col, (const float4*)tmp, dinv, bl, (float4*)h, 2);
        gatherp_k<2><<<G8_g, B, 0, stream>>>(rp2, col, (const float4*)tmp, dinv, bl, (float4*)h, 3);
    }

    pool_head_k<<<NUM_GRAPHS, B, 0, stream>>>(h, batch, Wout, bout, out);
}

// Round 7
// 607.477 us; speedup vs baseline: 1.4688x; 1.0915x over previous
//
#include <hip/hip_runtime.h>

#define N_NODES   100000
#define N_EDGES   3200000
#define NUM_GRAPHS 1024
#define F_IN      128
#define EMB       32

#define NRANGE    4
#define RANGE_SZ  25000                    // src ranges for phased gather
#define NKEY      (N_NODES * NRANGE)       // 400000 CSR keys (dst*4 + srcRange)

#define NGROUP    256                      // dst buckets
#define GROUP_SZ  391                      // 256*391 = 100096 >= N
#define BCAP      13824                    // mean 12512 + ~11.7 sigma
#define FB        1024                     // fill block threads
#define FILL_ITER 14                       // ceil(BCAP/FB)

#define PART_TILE 8192
#define PART_THREADS 512
#define PART_NB   ((N_EDGES + PART_TILE - 1) / PART_TILE)   // 391

// ---- tiny init: zero bucket counters; rp2 sentinel ----
__global__ void init_k(int* __restrict__ bucketCnt, int* __restrict__ rp2) {
    int i = threadIdx.x;
    if (i < NGROUP) bucketCnt[i] = 0;
    if (i == 0) rp2[NKEY] = N_EDGES;
}

// ---- partition edges into 256 dst-buckets, packed 4B, coalesced nt writes ----
__global__ __launch_bounds__(PART_THREADS) void partition_k(const int* __restrict__ src,
                                                            const int* __restrict__ dst,
                                                            int* __restrict__ bucketCnt,
                                                            unsigned* __restrict__ bEdges) {
    __shared__ unsigned stage[PART_TILE];
    __shared__ int hist[NGROUP];
    __shared__ int sc[NGROUP];
    __shared__ int lbase[NGROUP + 1];
    __shared__ int gbase[NGROUP];
    int t = threadIdx.x;
    int base = blockIdx.x * PART_TILE;
    for (int k = t; k < NGROUP; k += PART_THREADS) hist[k] = 0;
    __syncthreads();
    unsigned val[16]; int bk[16], rk[16];
#pragma unroll
    for (int i = 0; i < 16; ++i) {
        int e = base + i * PART_THREADS + t;
        bk[i] = -1;
        if (e < N_EDGES) {
            unsigned s = (unsigned)__builtin_nontemporal_load(src + e);
            unsigned d = (unsigned)__builtin_nontemporal_load(dst + e);
            int b = (int)(d / GROUP_SZ);
            val[i] = ((d - (unsigned)b * GROUP_SZ) << 17) | s;
            bk[i] = b;
            rk[i] = atomicAdd(&hist[b], 1);            // LDS atomic
        }
    }
    __syncthreads();
    if (t < NGROUP) sc[t] = hist[t];
    __syncthreads();
    for (int off = 1; off < NGROUP; off <<= 1) {       // Hillis inclusive scan
        int v = 0;
        if (t < NGROUP) v = sc[t] + ((t >= off) ? sc[t - off] : 0);
        __syncthreads();
        if (t < NGROUP) sc[t] = v;
        __syncthreads();
    }
    if (t < NGROUP) {
        lbase[t] = sc[t] - hist[t];
        if (hist[t] > 0) gbase[t] = atomicAdd(&bucketCnt[t], hist[t]);
        if (t == NGROUP - 1) lbase[NGROUP] = sc[t];
    }
    __syncthreads();
#pragma unroll
    for (int i = 0; i < 16; ++i)
        if (bk[i] >= 0) stage[lbase[bk[i]] + rk[i]] = val[i];
    __syncthreads();
    int total = lbase[NGROUP];
    for (int j = t; j < total; j += PART_THREADS) {
        int lo = 0, hi = NGROUP;
        while (hi - lo > 1) { int mid = (lo + hi) >> 1; if (lbase[mid] <= j) lo = mid; else hi = mid; }
        int off = gbase[lo] + (j - lbase[lo]);
        if (off < BCAP) __builtin_nontemporal_store(stage[j], &bEdges[(size_t)lo * BCAP + off]);
    }
}

// ---- per-bucket LDS counting sort: writes rp2 slice, dinv, col (all coalesced) ----
__global__ __launch_bounds__(FB) void fill_k(const unsigned* __restrict__ bEdges,
                                             const int* __restrict__ bucketCnt,
                                             int* __restrict__ rp2,
                                             float* __restrict__ dinv,
                                             int* __restrict__ col) {
    __shared__ int cur[GROUP_SZ * 4];
    __shared__ int nodesum[512];
    __shared__ unsigned lout[BCAP];
    __shared__ int sColBase;
    int b = blockIdx.x, t = threadIdx.x;

    if (t < NGROUP) { int c = bucketCnt[t]; nodesum[t] = c > BCAP ? BCAP : c; }
    else if (t < 512) nodesum[t] = 0;
    __syncthreads();
    for (int off = 1; off < NGROUP; off <<= 1) {
        int v = 0;
        if (t < NGROUP) v = nodesum[t] + ((t >= off) ? nodesum[t - off] : 0);
        __syncthreads();
        if (t < NGROUP) nodesum[t] = v;
        __syncthreads();
    }
    if (t == 0) sColBase = (b > 0) ? nodesum[b - 1] : 0;
    __syncthreads();
    int colBase = sColBase;

    int nb = N_NODES - b * GROUP_SZ; if (nb > GROUP_SZ) nb = GROUP_SZ;
    int nk = nb * 4;
    for (int k = t; k < nk; k += FB) cur[k] = 0;
    __syncthreads();

    int cnt = bucketCnt[b]; if (cnt > BCAP) cnt = BCAP;
    const unsigned* be = bEdges + (size_t)b * BCAP;
    unsigned val[FILL_ITER];
#pragma unroll
    for (int i = 0; i < FILL_ITER; ++i) {
        int idx = i * FB + t;
        val[i] = 0xFFFFFFFFu;
        if (idx < cnt) {
            unsigned v = __builtin_nontemporal_load(be + idx);
            val[i] = v;
            unsigned key = (v >> 17) * NRANGE + (v & 0x1FFFFu) / RANGE_SZ;
            atomicAdd(&cur[key], 1);
        }
    }
    __syncthreads();

    int h0 = 0, h1 = 0, h2 = 0, h3 = 0;
    if (t < nb) {
        h0 = cur[t * 4]; h1 = cur[t * 4 + 1]; h2 = cur[t * 4 + 2]; h3 = cur[t * 4 + 3];
        int dsum = h0 + h1 + h2 + h3;
        nodesum[t] = dsum;
        dinv[b * GROUP_SZ + t] = rsqrtf((float)(dsum + 1));
    } else if (t < 512) nodesum[t] = 0;
    __syncthreads();
    for (int off = 1; off < 512; off <<= 1) {
        int v = 0;
        if (t < 512) v = nodesum[t] + ((t >= off) ? nodesum[t - off] : 0);
        __syncthreads();
        if (t < 512) nodesum[t] = v;
        __syncthreads();
    }
    if (t < nb) {
        int p0 = (t > 0) ? nodesum[t - 1] : 0;
        int p1 = p0 + h0, p2 = p1 + h1, p3 = p2 + h2;
        int kb = (b * GROUP_SZ + t) * 4;
        int4 w; w.x = colBase + p0; w.y = colBase + p1; w.z = colBase + p2; w.w = colBase + p3;
        *(int4*)(rp2 + kb) = w;
        cur[t * 4] = p0; cur[t * 4 + 1] = p1; cur[t * 4 + 2] = p2; cur[t * 4 + 3] = p3;
    }
    __syncthreads();

#pragma unroll
    for (int i = 0; i < FILL_ITER; ++i) {
        unsigned v = val[i];
        if (v != 0xFFFFFFFFu) {
            unsigned key = (v >> 17) * NRANGE + (v & 0x1FFFFu) / RANGE_SZ;
            int slot = atomicAdd(&cur[key], 1);
            lout[slot] = v & 0x1FFFFu;
        }
    }
    __syncthreads();

    for (int i = t; i < cnt; i += FB)
        __builtin_nontemporal_store((int)lout[i], col + colBase + i);
}

// ---- layer 0 transform (vectorized): thread = (node, 4-ch quad) ----
// tmp[n][q*4..+3] = (x[n,:] @ W0[:,q*4..+3]) * dinv[n]; k-order preserved.
__global__ __launch_bounds__(256) void transform0_k(const float* __restrict__ x,
                                                    const float* __restrict__ W0,
                                                    const float* __restrict__ dinv,
                                                    float4* __restrict__ tmp4) {
    int i = blockIdx.x * blockDim.x + threadIdx.x;
    if (i >= N_NODES * 8) return;
    int n = i >> 3, q = i & 7;
    const float4* xr = (const float4*)(x + (long long)n * F_IN);
    const float* wq = W0 + q * 4;
    float4 acc = {0.f, 0.f, 0.f, 0.f};
#pragma unroll 8
    for (int kc = 0; kc < F_IN / 4; ++kc) {
        float4 xv = xr[kc];
        float4 w0 = *(const float4*)(wq + (kc * 4 + 0) * EMB);
        float4 w1 = *(const float4*)(wq + (kc * 4 + 1) * EMB);
        float4 w2 = *(const float4*)(wq + (kc * 4 + 2) * EMB);
        float4 w3 = *(const float4*)(wq + (kc * 4 + 3) * EMB);
        acc.x += xv.x * w0.x; acc.y += xv.x * w0.y; acc.z += xv.x * w0.z; acc.w += xv.x * w0.w;
        acc.x += xv.y * w1.x; acc.y += xv.y * w1.y; acc.z += xv.y * w1.z; acc.w += xv.y * w1.w;
        acc.x += xv.z * w2.x; acc.y += xv.z * w2.y; acc.z += xv.z * w2.z; acc.w += xv.z * w2.w;
        acc.x += xv.w * w3.x; acc.y += xv.w * w3.y; acc.z += xv.w * w3.z; acc.w += xv.w * w3.w;
    }
    float dn = dinv[n];
    acc.x *= dn; acc.y *= dn; acc.z *= dn; acc.w *= dn;
    tmp4[i] = acc;
}

// ---- hidden transform (vectorized, K=32) ----
__global__ __launch_bounds__(256) void transform_k(const float* __restrict__ h,
                                                   const float* __restrict__ W,
                                                   const float* __restrict__ dinv,
                                                   float4* __restrict__ tmp4) {
    int i = blockIdx.x * blockDim.x + threadIdx.x;
    if (i >= N_NODES * 8) return;
    int n = i >> 3, q = i & 7;
    const float4* hr = (const float4*)(h + n * EMB);
    const float* wq = W + q * 4;
    float4 acc = {0.f, 0.f, 0.f, 0.f};
#pragma unroll
    for (int kc = 0; kc < EMB / 4; ++kc) {
        float4 xv = hr[kc];
        float4 w0 = *(const float4*)(wq + (kc * 4 + 0) * EMB);
        float4 w1 = *(const float4*)(wq + (kc * 4 + 1) * EMB);
        float4 w2 = *(const float4*)(wq + (kc * 4 + 2) * EMB);
        float4 w3 = *(const float4*)(wq + (kc * 4 + 3) * EMB);
        acc.x += xv.x * w0.x; acc.y += xv.x * w0.y; acc.z += xv.x * w0.z; acc.w += xv.x * w0.w;
        acc.x += xv.y * w1.x; acc.y += xv.y * w1.y; acc.z += xv.y * w1.z; acc.w += xv.y * w1.w;
        acc.x += xv.z * w2.x; acc.y += xv.z * w2.y; acc.z += xv.z * w2.z; acc.w += xv.z * w2.w;
        acc.x += xv.w * w3.x; acc.y += xv.w * w3.y; acc.z += xv.w * w3.z; acc.w += xv.w * w3.w;
    }
    float dn = dinv[n];
    acc.x *= dn; acc.y *= dn; acc.z *= dn; acc.w *= dn;
    tmp4[i] = acc;
}

// ---- phased gather: phase r touches only tmp slice [r*25000,(r+1)*25000) ----
template <int MODE>   // 0: acc=tmp(self)  1: acc=h  2: acc=h then finalize
__global__ void gatherp_k(const int* __restrict__ rp2, const int* __restrict__ col,
                          const float4* __restrict__ tmp4, const float* __restrict__ dinv,
                          const float* __restrict__ bias, float4* __restrict__ h4, int r) {
    int i = blockIdx.x * blockDim.x + threadIdx.x;
    if (i >= N_NODES * 8) return;
    int n = i >> 3, q = i & 7;
    int beg = rp2[n * 4 + r], end = rp2[n * 4 + r + 1];
    float4 acc = (MODE == 0) ? tmp4[i] : h4[i];
    int k = beg;
    for (; k + 4 <= end; k += 4) {
        int s0 = col[k], s1 = col[k + 1], s2 = col[k + 2], s3 = col[k + 3];
        float4 v0 = tmp4[s0 * 8 + q];
        float4 v1 = tmp4[s1 * 8 + q];
        float4 v2 = tmp4[s2 * 8 + q];
        float4 v3 = tmp4[s3 * 8 + q];
        acc.x += (v0.x + v1.x) + (v2.x + v3.x);
        acc.y += (v0.y + v1.y) + (v2.y + v3.y);
        acc.z += (v0.z + v1.z) + (v2.z + v3.z);
        acc.w += (v0.w + v1.w) + (v2.w + v3.w);
    }
    for (; k < end; ++k) {
        int s = col[k];
        float4 v = tmp4[s * 8 + q];
        acc.x += v.x; acc.y += v.y; acc.z += v.z; acc.w += v.w;
    }
    if (MODE == 2) {
        float dn = dinv[n];
        float4 bb = ((const float4*)bias)[q];
        float4 rr;
        rr.x = acc.x * dn + bb.x;
        rr.y = acc.y * dn + bb.y;
        rr.z = acc.z * dn + bb.z;
        rr.w = acc.w * dn + bb.w;
        rr.x = rr.x > 0.f ? rr.x : 0.01f * rr.x;
        rr.y = rr.y > 0.f ? rr.y : 0.01f * rr.y;
        rr.z = rr.z > 0.f ? rr.z : 0.01f * rr.z;
        rr.w = rr.w > 0.f ? rr.w : 0.01f * rr.w;
        h4[i] = rr;
    } else {
        h4[i] = acc;
    }
}

// ---- fused pool + head (batch_index sorted) ----
__global__ __launch_bounds__(256) void pool_head_k(const float* __restrict__ h,
                                                   const int* __restrict__ batch,
                                                   const float* __restrict__ Wout,
                                                   const float* __restrict__ bout,
                                                   float* __restrict__ out) {
    int g = blockIdx.x;
    __shared__ int sbeg, send;
    if (threadIdx.x == 0) {
        int lo = 0, hi = N_NODES;
        while (lo < hi) { int mid = (lo + hi) >> 1; if (batch[mid] < g) lo = mid + 1; else hi = mid; }
        sbeg = lo;
        hi = N_NODES;
        while (lo < hi) { int mid = (lo + hi) >> 1; if (batch[mid] < g + 1) lo = mid + 1; else hi = mid; }
        send = lo;
    }
    __syncthreads();
    int beg = sbeg, end = send;
    int t = threadIdx.x, c = t & 31, r = t >> 5;
    float m = -INFINITY;
    for (int n = beg + r; n < end; n += 8) m = fmaxf(m, h[n * EMB + c]);
    __shared__ float red[256];
    red[t] = m;
    __syncthreads();
    if (t < 128) red[t] = fmaxf(red[t], red[t + 128]);
    __syncthreads();
    if (t < 64) red[t] = fmaxf(red[t], red[t + 64]);
    __syncthreads();
    if (t < 32) {
        m = fmaxf(red[t], red[t + 32]);
        out[NUM_GRAPHS + g * EMB + c] = m;
        float p = m * Wout[c];
#pragma unroll
        for (int o = 16; o > 0; o >>= 1) p += __shfl_xor(p, o, 32);
        if (c == 0) out[g] = p + bout[0];
    }
}

extern "C" void kernel_launch(void* const* d_in, const int* in_sizes, int n_in,
                              void* d_out, int out_size, void* d_ws, size_t ws_size,
                              hipStream_t stream) {
    const float* x     = (const float*)d_in[0];
    const int*   ei    = (const int*)d_in[1];
    const int*   src   = ei;
    const int*   dst   = ei + N_EDGES;
    const int*   batch = (const int*)d_in[2];
    const float* W0    = (const float*)d_in[3];
    const float* b0    = (const float*)d_in[4];
    const float* Ws    = (const float*)d_in[5];
    const float* bs    = (const float*)d_in[6];
    const float* Wout  = (const float*)d_in[7];
    const float* bout  = (const float*)d_in[8];
    float* out = (float*)d_out;

    char* ws = (char*)d_ws;
    int*   rp2      = (int*)ws;   ws += (size_t)(NKEY + 4) * 4;        // 1.6 MB
    int*   col      = (int*)ws;   ws += (size_t)N_EDGES * 4;           // 12.8 MB
    float* dinv     = (float*)ws; ws += (size_t)N_NODES * 4;           // 400 KB
    float* tmp      = (float*)ws; ws += (size_t)N_NODES * EMB * 4;     // 12.8 MB
    float* h        = (float*)ws; ws += (size_t)N_NODES * EMB * 4;     // 12.8 MB
    int*   bucketCnt= (int*)ws;   ws += 1024;                          // 256 ints
    unsigned* bEdges = (unsigned*)tmp;   // 14.2 MB alias over tmp+h, dead before transforms

    const int B = 256;
    const int G8_g = (N_NODES * 8 + B - 1) / B;

    init_k<<<1, B, 0, stream>>>(bucketCnt, rp2);
    partition_k<<<PART_NB, PART_THREADS, 0, stream>>>(src, dst, bucketCnt, bEdges);
    fill_k<<<NGROUP, FB, 0, stream>>>(bEdges, bucketCnt, rp2, dinv, col);

    // layer 0: 128 -> 32
    transform0_k<<<G8_g, B, 0, stream>>>(x, W0, dinv, (float4*)tmp);
    gatherp_k<0><<<G8_g, B, 0, stream>>>(rp2, col, (const float4*)tmp, dinv, b0, (float4*)h, 0);
    gatherp_k<1><<<G8_g, B, 0, stream>>>(rp2, col, (const float4*)tmp, dinv, b0, (float4*)h, 1);
    gatherp_k<1><<<G8_g, B, 0, stream>>>(rp2, col, (const float4*)tmp, dinv, b0, (float4*)h, 2);
    gatherp_k<2><<<G8_g, B, 0, stream>>>(rp2, col, (const float4*)tmp, dinv, b0, (float4*)h, 3);

    // hidden layers: 32 -> 32
    for (int l = 0; l < 3; ++l) {
        const float* bl = bs + l * EMB;
        transform_k<<<G8_g, B, 0, stream>>>(h, Ws + l * EMB * EMB, dinv, (float4*)tmp);
        gatherp_k<0><<<G8_g, B, 0, stream>>>(rp2, col, (const float4*)tmp, dinv, bl, (float4*)h, 0);
        gatherp_k<1><<<G8_g, B, 0, stream>>>(rp2, col, (const float4*)tmp, dinv, bl, (float4*)h, 1);
        gatherp_k<1><<<G8_g, B, 0, stream>>>(rp2, col, (const float4*)tmp, dinv, bl, (float4*)h, 2);
        gatherp_k<2><<<G8_g, B, 0, stream>>>(rp2, col, (const float4*)tmp, dinv, bl, (float4*)h, 3);
    }

    pool_head_k<<<NUM_GRAPHS, B, 0, stream>>>(h, batch, Wout, bout, out);
}

// Round 8
// 500.671 us; speedup vs baseline: 1.7821x; 1.2133x over previous
//
#include <hip/hip_runtime.h>

#define N_NODES   100000
#define N_EDGES   3200000
#define NUM_GRAPHS 1024
#define F_IN      128
#define EMB       32

#define NRANGE    4
#define RANGE_SZ  25000                    // src ranges for phased gather
#define NKEY      (N_NODES * NRANGE)       // 400000 CSR keys (dst*4 + srcRange)

#define NGROUP    256                      // dst buckets
#define GROUP_SZ  391                      // 256*391 = 100096 >= N
#define BCAP      13824                    // mean 12512 + ~11.7 sigma
#define FB        1024                     // fill block threads
#define FILL_ITER 14                       // ceil(BCAP/FB)

#define PART_TILE 8192
#define PART_THREADS 512
#define PART_NB   ((N_EDGES + PART_TILE - 1) / PART_TILE)   // 391

// ---- tiny init: zero bucket counters; rp2 sentinel ----
__global__ void init_k(int* __restrict__ bucketCnt, int* __restrict__ rp2) {
    int i = threadIdx.x;
    if (i < NGROUP) bucketCnt[i] = 0;
    if (i == 0) rp2[NKEY] = N_EDGES;
}

// ---- partition edges into 256 dst-buckets, packed 4B, coalesced nt writes ----
__global__ __launch_bounds__(PART_THREADS) void partition_k(const int* __restrict__ src,
                                                            const int* __restrict__ dst,
                                                            int* __restrict__ bucketCnt,
                                                            unsigned* __restrict__ bEdges) {
    __shared__ unsigned stage[PART_TILE];
    __shared__ int hist[NGROUP];
    __shared__ int sc[NGROUP];
    __shared__ int lbase[NGROUP + 1];
    __shared__ int gbase[NGROUP];
    int t = threadIdx.x;
    int base = blockIdx.x * PART_TILE;
    for (int k = t; k < NGROUP; k += PART_THREADS) hist[k] = 0;
    __syncthreads();
    unsigned val[16]; int bk[16], rk[16];
#pragma unroll
    for (int i = 0; i < 16; ++i) {
        int e = base + i * PART_THREADS + t;
        bk[i] = -1;
        if (e < N_EDGES) {
            unsigned s = (unsigned)__builtin_nontemporal_load(src + e);
            unsigned d = (unsigned)__builtin_nontemporal_load(dst + e);
            int b = (int)(d / GROUP_SZ);
            val[i] = ((d - (unsigned)b * GROUP_SZ) << 17) | s;
            bk[i] = b;
            rk[i] = atomicAdd(&hist[b], 1);            // LDS atomic
        }
    }
    __syncthreads();
    if (t < NGROUP) sc[t] = hist[t];
    __syncthreads();
    for (int off = 1; off < NGROUP; off <<= 1) {       // Hillis inclusive scan
        int v = 0;
        if (t < NGROUP) v = sc[t] + ((t >= off) ? sc[t - off] : 0);
        __syncthreads();
        if (t < NGROUP) sc[t] = v;
        __syncthreads();
    }
    if (t < NGROUP) {
        lbase[t] = sc[t] - hist[t];
        if (hist[t] > 0) gbase[t] = atomicAdd(&bucketCnt[t], hist[t]);
        if (t == NGROUP - 1) lbase[NGROUP] = sc[t];
    }
    __syncthreads();
#pragma unroll
    for (int i = 0; i < 16; ++i)
        if (bk[i] >= 0) stage[lbase[bk[i]] + rk[i]] = val[i];
    __syncthreads();
    int total = lbase[NGROUP];
    for (int j = t; j < total; j += PART_THREADS) {
        int lo = 0, hi = NGROUP;
        while (hi - lo > 1) { int mid = (lo + hi) >> 1; if (lbase[mid] <= j) lo = mid; else hi = mid; }
        int off = gbase[lo] + (j - lbase[lo]);
        if (off < BCAP) __builtin_nontemporal_store(stage[j], &bEdges[(size_t)lo * BCAP + off]);
    }
}

// ---- per-bucket LDS counting sort: writes rp2 slice, dinv, col (all coalesced) ----
__global__ __launch_bounds__(FB) void fill_k(const unsigned* __restrict__ bEdges,
                                             const int* __restrict__ bucketCnt,
                                             int* __restrict__ rp2,
                                             float* __restrict__ dinv,
                                             int* __restrict__ col) {
    __shared__ int cur[GROUP_SZ * 4];
    __shared__ int nodesum[512];
    __shared__ unsigned lout[BCAP];
    __shared__ int sColBase;
    int b = blockIdx.x, t = threadIdx.x;

    if (t < NGROUP) { int c = bucketCnt[t]; nodesum[t] = c > BCAP ? BCAP : c; }
    else if (t < 512) nodesum[t] = 0;
    __syncthreads();
    for (int off = 1; off < NGROUP; off <<= 1) {
        int v = 0;
        if (t < NGROUP) v = nodesum[t] + ((t >= off) ? nodesum[t - off] : 0);
        __syncthreads();
        if (t < NGROUP) nodesum[t] = v;
        __syncthreads();
    }
    if (t == 0) sColBase = (b > 0) ? nodesum[b - 1] : 0;
    __syncthreads();
    int colBase = sColBase;

    int nb = N_NODES - b * GROUP_SZ; if (nb > GROUP_SZ) nb = GROUP_SZ;
    int nk = nb * 4;
    for (int k = t; k < nk; k += FB) cur[k] = 0;
    __syncthreads();

    int cnt = bucketCnt[b]; if (cnt > BCAP) cnt = BCAP;
    const unsigned* be = bEdges + (size_t)b * BCAP;
    unsigned val[FILL_ITER];
#pragma unroll
    for (int i = 0; i < FILL_ITER; ++i) {
        int idx = i * FB + t;
        val[i] = 0xFFFFFFFFu;
        if (idx < cnt) {
            unsigned v = __builtin_nontemporal_load(be + idx);
            val[i] = v;
            unsigned key = (v >> 17) * NRANGE + (v & 0x1FFFFu) / RANGE_SZ;
            atomicAdd(&cur[key], 1);
        }
    }
    __syncthreads();

    int h0 = 0, h1 = 0, h2 = 0, h3 = 0;
    if (t < nb) {
        h0 = cur[t * 4]; h1 = cur[t * 4 + 1]; h2 = cur[t * 4 + 2]; h3 = cur[t * 4 + 3];
        int dsum = h0 + h1 + h2 + h3;
        nodesum[t] = dsum;
        dinv[b * GROUP_SZ + t] = rsqrtf((float)(dsum + 1));
    } else if (t < 512) nodesum[t] = 0;
    __syncthreads();
    for (int off = 1; off < 512; off <<= 1) {
        int v = 0;
        if (t < 512) v = nodesum[t] + ((t >= off) ? nodesum[t - off] : 0);
        __syncthreads();
        if (t < 512) nodesum[t] = v;
        __syncthreads();
    }
    if (t < nb) {
        int p0 = (t > 0) ? nodesum[t - 1] : 0;
        int p1 = p0 + h0, p2 = p1 + h1, p3 = p2 + h2;
        int kb = (b * GROUP_SZ + t) * 4;
        int4 w; w.x = colBase + p0; w.y = colBase + p1; w.z = colBase + p2; w.w = colBase + p3;
        *(int4*)(rp2 + kb) = w;
        cur[t * 4] = p0; cur[t * 4 + 1] = p1; cur[t * 4 + 2] = p2; cur[t * 4 + 3] = p3;
    }
    __syncthreads();

#pragma unroll
    for (int i = 0; i < FILL_ITER; ++i) {
        unsigned v = val[i];
        if (v != 0xFFFFFFFFu) {
            unsigned key = (v >> 17) * NRANGE + (v & 0x1FFFFu) / RANGE_SZ;
            int slot = atomicAdd(&cur[key], 1);
            lout[slot] = v & 0x1FFFFu;
        }
    }
    __syncthreads();

    for (int i = t; i < cnt; i += FB)
        __builtin_nontemporal_store((int)lout[i], col + colBase + i);
}

// ---- layer 0 transform, register-blocked: thread = (8-node group, channel quad) ----
// Per kc: 4 W-quad loads (coalesced across q-lanes) amortized over 8 nodes.
// Accumulation per channel stays k-ascending (bit-identical to previous rounds).
__global__ __launch_bounds__(256) void transform0_k(const float* __restrict__ x,
                                                    const float* __restrict__ W0,
                                                    const float* __restrict__ dinv,
                                                    float4* __restrict__ tmp4) {
    int i = blockIdx.x * blockDim.x + threadIdx.x;   // 100000 threads
    if (i >= (N_NODES / 8) * 8) return;
    int gid = i >> 3, q = i & 7;
    int n0 = gid * 8;
    const float* wq = W0 + q * 4;
    float4 acc[8];
#pragma unroll
    for (int j = 0; j < 8; ++j) acc[j] = make_float4(0.f, 0.f, 0.f, 0.f);
#pragma unroll 2
    for (int kc = 0; kc < F_IN / 4; ++kc) {
        float4 w0 = *(const float4*)(wq + (kc * 4 + 0) * EMB);
        float4 w1 = *(const float4*)(wq + (kc * 4 + 1) * EMB);
        float4 w2 = *(const float4*)(wq + (kc * 4 + 2) * EMB);
        float4 w3 = *(const float4*)(wq + (kc * 4 + 3) * EMB);
#pragma unroll
        for (int j = 0; j < 8; ++j) {
            float4 xv = *(const float4*)(x + (long long)(n0 + j) * F_IN + kc * 4);
            acc[j].x += xv.x * w0.x; acc[j].y += xv.x * w0.y; acc[j].z += xv.x * w0.z; acc[j].w += xv.x * w0.w;
            acc[j].x += xv.y * w1.x; acc[j].y += xv.y * w1.y; acc[j].z += xv.y * w1.z; acc[j].w += xv.y * w1.w;
            acc[j].x += xv.z * w2.x; acc[j].y += xv.z * w2.y; acc[j].z += xv.z * w2.z; acc[j].w += xv.z * w2.w;
            acc[j].x += xv.w * w3.x; acc[j].y += xv.w * w3.y; acc[j].z += xv.w * w3.z; acc[j].w += xv.w * w3.w;
        }
    }
#pragma unroll
    for (int j = 0; j < 8; ++j) {
        float dn = dinv[n0 + j];
        acc[j].x *= dn; acc[j].y *= dn; acc[j].z *= dn; acc[j].w *= dn;
        tmp4[(n0 + j) * 8 + q] = acc[j];
    }
}

// ---- hidden transform, register-blocked (K=32) ----
__global__ __launch_bounds__(256) void transform_k(const float* __restrict__ h,
                                                   const float* __restrict__ W,
                                                   const float* __restrict__ dinv,
                                                   float4* __restrict__ tmp4) {
    int i = blockIdx.x * blockDim.x + threadIdx.x;
    if (i >= (N_NODES / 8) * 8) return;
    int gid = i >> 3, q = i & 7;
    int n0 = gid * 8;
    const float* wq = W + q * 4;
    float4 acc[8];
#pragma unroll
    for (int j = 0; j < 8; ++j) acc[j] = make_float4(0.f, 0.f, 0.f, 0.f);
#pragma unroll
    for (int kc = 0; kc < EMB / 4; ++kc) {
        float4 w0 = *(const float4*)(wq + (kc * 4 + 0) * EMB);
        float4 w1 = *(const float4*)(wq + (kc * 4 + 1) * EMB);
        float4 w2 = *(const float4*)(wq + (kc * 4 + 2) * EMB);
        float4 w3 = *(const float4*)(wq + (kc * 4 + 3) * EMB);
#pragma unroll
        for (int j = 0; j < 8; ++j) {
            float4 xv = *(const float4*)(h + (n0 + j) * EMB + kc * 4);
            acc[j].x += xv.x * w0.x; acc[j].y += xv.x * w0.y; acc[j].z += xv.x * w0.z; acc[j].w += xv.x * w0.w;
            acc[j].x += xv.y * w1.x; acc[j].y += xv.y * w1.y; acc[j].z += xv.y * w1.z; acc[j].w += xv.y * w1.w;
            acc[j].x += xv.z * w2.x; acc[j].y += xv.z * w2.y; acc[j].z += xv.z * w2.z; acc[j].w += xv.z * w2.w;
            acc[j].x += xv.w * w3.x; acc[j].y += xv.w * w3.y; acc[j].z += xv.w * w3.z; acc[j].w += xv.w * w3.w;
        }
    }
#pragma unroll
    for (int j = 0; j < 8; ++j) {
        float dn = dinv[n0 + j];
        acc[j].x *= dn; acc[j].y *= dn; acc[j].z *= dn; acc[j].w *= dn;
        tmp4[(n0 + j) * 8 + q] = acc[j];
    }
}

// ---- fused gather: all 4 src-range phases in-register; finalize at end ----
__global__ void gather_k(const int* __restrict__ rp2, const int* __restrict__ col,
                         const float4* __restrict__ tmp4, const float* __restrict__ dinv,
                         const float* __restrict__ bias, float4* __restrict__ h4) {
    int i = blockIdx.x * blockDim.x + threadIdx.x;
    if (i >= N_NODES * 8) return;
    int n = i >> 3, q = i & 7;
    float4 acc = tmp4[i];                       // self-loop term
#pragma unroll
    for (int r = 0; r < NRANGE; ++r) {
        int k = rp2[n * 4 + r], end = rp2[n * 4 + r + 1];
        // scalar prologue to 16B alignment (keeps k-ascending order)
        for (; k < end && (k & 3); ++k) {
            float4 v = tmp4[col[k] * 8 + q];
            acc.x += v.x; acc.y += v.y; acc.z += v.z; acc.w += v.w;
        }
        for (; k + 4 <= end; k += 4) {
            int4 c = *(const int4*)(col + k);
            float4 v0 = tmp4[c.x * 8 + q];
            float4 v1 = tmp4[c.y * 8 + q];
            float4 v2 = tmp4[c.z * 8 + q];
            float4 v3 = tmp4[c.w * 8 + q];
            acc.x += (v0.x + v1.x) + (v2.x + v3.x);
            acc.y += (v0.y + v1.y) + (v2.y + v3.y);
            acc.z += (v0.z + v1.z) + (v2.z + v3.z);
            acc.w += (v0.w + v1.w) + (v2.w + v3.w);
        }
        for (; k < end; ++k) {
            float4 v = tmp4[col[k] * 8 + q];
            acc.x += v.x; acc.y += v.y; acc.z += v.z; acc.w += v.w;
        }
    }
    float dn = dinv[n];
    float4 bb = ((const float4*)bias)[q];
    float4 rr;
    rr.x = acc.x * dn + bb.x;
    rr.y = acc.y * dn + bb.y;
    rr.z = acc.z * dn + bb.z;
    rr.w = acc.w * dn + bb.w;
    rr.x = rr.x > 0.f ? rr.x : 0.01f * rr.x;
    rr.y = rr.y > 0.f ? rr.y : 0.01f * rr.y;
    rr.z = rr.z > 0.f ? rr.z : 0.01f * rr.z;
    rr.w = rr.w > 0.f ? rr.w : 0.01f * rr.w;
    h4[i] = rr;
}

// ---- fused pool + head (batch_index sorted) ----
__global__ __launch_bounds__(256) void pool_head_k(const float* __restrict__ h,
                                                   const int* __restrict__ batch,
                                                   const float* __restrict__ Wout,
                                                   const float* __restrict__ bout,
                                                   float* __restrict__ out) {
    int g = blockIdx.x;
    __shared__ int sbeg, send;
    if (threadIdx.x == 0) {
        int lo = 0, hi = N_NODES;
        while (lo < hi) { int mid = (lo + hi) >> 1; if (batch[mid] < g) lo = mid + 1; else hi = mid; }
        sbeg = lo;
        hi = N_NODES;
        while (lo < hi) { int mid = (lo + hi) >> 1; if (batch[mid] < g + 1) lo = mid + 1; else hi = mid; }
        send = lo;
    }
    __syncthreads();
    int beg = sbeg, end = send;
    int t = threadIdx.x, c = t & 31, r = t >> 5;
    float m = -INFINITY;
    for (int n = beg + r; n < end; n += 8) m = fmaxf(m, h[n * EMB + c]);
    __shared__ float red[256];
    red[t] = m;
    __syncthreads();
    if (t < 128) red[t] = fmaxf(red[t], red[t + 128]);
    __syncthreads();
    if (t < 64) red[t] = fmaxf(red[t], red[t + 64]);
    __syncthreads();
    if (t < 32) {
        m = fmaxf(red[t], red[t + 32]);
        out[NUM_GRAPHS + g * EMB + c] = m;
        float p = m * Wout[c];
#pragma unroll
        for (int o = 16; o > 0; o >>= 1) p += __shfl_xor(p, o, 32);
        if (c == 0) out[g] = p + bout[0];
    }
}

extern "C" void kernel_launch(void* const* d_in, const int* in_sizes, int n_in,
                              void* d_out, int out_size, void* d_ws, size_t ws_size,
                              hipStream_t stream) {
    const float* x     = (const float*)d_in[0];
    const int*   ei    = (const int*)d_in[1];
    const int*   src   = ei;
    const int*   dst   = ei + N_EDGES;
    const int*   batch = (const int*)d_in[2];
    const float* W0    = (const float*)d_in[3];
    const float* b0    = (const float*)d_in[4];
    const float* Ws    = (const float*)d_in[5];
    const float* bs    = (const float*)d_in[6];
    const float* Wout  = (const float*)d_in[7];
    const float* bout  = (const float*)d_in[8];
    float* out = (float*)d_out;

    char* ws = (char*)d_ws;
    int*   rp2      = (int*)ws;   ws += (size_t)(NKEY + 4) * 4;        // 1.6 MB
    int*   col      = (int*)ws;   ws += (size_t)N_EDGES * 4;           // 12.8 MB
    float* dinv     = (float*)ws; ws += (size_t)N_NODES * 4;           // 400 KB
    float* tmp      = (float*)ws; ws += (size_t)N_NODES * EMB * 4;     // 12.8 MB
    float* h        = (float*)ws; ws += (size_t)N_NODES * EMB * 4;     // 12.8 MB
    int*   bucketCnt= (int*)ws;   ws += 1024;                          // 256 ints
    unsigned* bEdges = (unsigned*)tmp;   // 14.2 MB alias over tmp+h, dead before transforms

    const int B = 256;
    const int G8_g = (N_NODES * 8 + B - 1) / B;
    const int T_g  = (N_NODES + B - 1) / B;              // 100000 threads

    init_k<<<1, B, 0, stream>>>(bucketCnt, rp2);
    partition_k<<<PART_NB, PART_THREADS, 0, stream>>>(src, dst, bucketCnt, bEdges);
    fill_k<<<NGROUP, FB, 0, stream>>>(bEdges, bucketCnt, rp2, dinv, col);

    // layer 0: 128 -> 32
    transform0_k<<<T_g, B, 0, stream>>>(x, W0, dinv, (float4*)tmp);
    gather_k<<<G8_g, B, 0, stream>>>(rp2, col, (const float4*)tmp, dinv, b0, (float4*)h);

    // hidden layers: 32 -> 32
    for (int l = 0; l < 3; ++l) {
        transform_k<<<T_g, B, 0, stream>>>(h, Ws + l * EMB * EMB, dinv, (float4*)tmp);
        gather_k<<<G8_g, B, 0, stream>>>(rp2, col, (const float4*)tmp, dinv, bs + l * EMB, (float4*)h);
    }

    pool_head_k<<<NUM_GRAPHS, B, 0, stream>>>(h, batch, Wout, bout, out);
}